// Round 4
// baseline (11254.369 us; speedup 1.0000x reference)
//
#include <hip/hip_runtime.h>
#include <math.h>

#define NB 64      // batch
#define NH 512     // hidden
#define NV 64      // vocab
#define NT 200     // T
#define NSTEP 199
#define GBLK 256   // main-loop blocks
#define GTHR 512   // threads per block

#define RLX   __ATOMIC_RELAXED
#define AGENT __HIP_MEMORY_SCOPE_AGENT

typedef float f4v __attribute__((ext_vector_type(4)));

// ---------------- threefry / gumbel --------------------------------------
// jax.random.categorical(jax.random.key(1),...) with jax_threefry_partitionable=True:
// bits = x0^x1 of threefry2x32(key=(0,1), counter=(0, flat_index))
__device__ inline float gumbel_tf(unsigned f){
  const unsigned ksc[3] = {0u, 1u, 0x1BD11BDBu};
  unsigned x0 = 0u + ksc[0];
  unsigned x1 = f  + ksc[1];
  const int R0[4] = {13,15,26,6};
  const int R1[4] = {17,29,16,24};
  #pragma unroll
  for (int i = 0; i < 5; ++i){
    #pragma unroll
    for (int r = 0; r < 4; ++r){
      int rot = (i & 1) ? R1[r] : R0[r];
      x0 += x1;
      x1 = (x1 << rot) | (x1 >> (32 - rot));
      x1 ^= x0;
    }
    x0 += ksc[(i+1)%3];
    x1 += ksc[(i+2)%3] + (unsigned)(i+1);
  }
  unsigned bits = x0 ^ x1;
  float u = __uint_as_float((bits >> 9) | 0x3F800000u) - 1.0f;
  u = fmaxf(u, 1.17549435e-38f);
  return -logf(-logf(u));
}

__device__ inline float sigf(float x){ return 1.0f/(1.0f + expf(-x)); }

// ---------------- grid barrier: single-level monotone counter, no fences.
// All cross-block data was stored via returning agent-scope atomic-exchange and
// drained (vmcnt(0)) before arrival; reads use sc0sc1 loads (validated R3 scheme).
__device__ inline void gbar(unsigned* cnt, unsigned* gen, unsigned tgt){
  asm volatile("s_waitcnt vmcnt(0)" ::: "memory");
  __syncthreads();
  if (threadIdx.x == 0){
    unsigned a = __hip_atomic_fetch_add(cnt, 1u, RLX, AGENT);
    if ((a & 255u) == 255u){
      unsigned t = __hip_atomic_fetch_add(gen, 1u, RLX, AGENT);
      asm volatile("" :: "v"(t));
    }
    while (__hip_atomic_load(gen, RLX, AGENT) < tgt){
      __builtin_amdgcn_s_sleep(2);
    }
  }
  __syncthreads();
}

// ---------------- precompute kernels ----------------
__global__ void k_msum_part(const float* __restrict__ emb, const int* __restrict__ lens,
                            float* __restrict__ part){
  int blk = blockIdx.x, b = blk >> 3, lc = blk & 7;
  int len = lens[b];
  int l0 = lc*64, l1 = len < l0+64 ? len : l0+64;
  for (int h = threadIdx.x; h < 512; h += 256){
    float a = 0.f;
    for (int l = l0; l < l1; ++l) a += emb[(b*512 + l)*512 + h];
    part[blk*512 + h] = a;
  }
}
__global__ void k_msum(const float* __restrict__ part, float* __restrict__ msumT){
  int b = blockIdx.x;
  for (int h = threadIdx.x; h < 512; h += 256){
    float a = 0.f;
    #pragma unroll
    for (int lc = 0; lc < 8; ++lc) a += part[(b*8+lc)*512 + h];
    msumT[h*64 + b] = a;
  }
}
__global__ void k_kv(const float* __restrict__ msumT,
                     const float* __restrict__ kw, const float* __restrict__ kb,
                     const float* __restrict__ vw, const float* __restrict__ vb,
                     float* __restrict__ keysum, float* __restrict__ valsum){
  int which = blockIdx.x >> 7;
  int i = ((blockIdx.x & 127) << 2) + (threadIdx.x >> 6);
  int b = threadIdx.x & 63;
  const float* W = which ? vw : kw;
  float a = 0.f;
  for (int h = 0; h < 512; ++h) a = fmaf(msumT[h*64+b], W[i*512+h], a);
  float bias = which ? vb[i] : kb[i];
  float* out = which ? valsum : keysum;
  out[b*512 + i] = a + 512.0f*bias;
}
__global__ void k_ceT(const float* __restrict__ ce, float* __restrict__ ceT){
  int idx = blockIdx.x*256 + threadIdx.x;
  if (idx < 32768){ int v = idx >> 9, e = idx & 511; ceT[e*64 + v] = ce[v*512 + e]; }
}
__global__ void k_tok(const float* __restrict__ ceT, const float* __restrict__ w_ih,
                      const float* __restrict__ b_ih, const float* __restrict__ b_hh,
                      float* __restrict__ tok){
  int idx = blockIdx.x*256 + threadIdx.x;
  int v = idx & 63, row = idx >> 6;
  float a = 0.f;
  for (int e = 0; e < 512; ++e) a = fmaf(ceT[e*64+v], w_ih[row*1024 + e], a);
  tok[v*2048 + row] = a + b_ih[row] + b_hh[row];
}
// fold keysum->ksT (scaled by log2e/sqrt(H)), valsum->vsT, zero h-buffers, out row0, bar
__global__ void k_init(const float* __restrict__ keysum, const float* __restrict__ valsum,
                       float* __restrict__ ksT, float* __restrict__ vsT,
                       float* __restrict__ hbuf, float* __restrict__ out,
                       unsigned* __restrict__ bar){
  const float C = 1.4426950408889634f / 22.627416997969522f;  // log2(e)/sqrt(512)
  int idx = blockIdx.x*256 + threadIdx.x;
  if (idx < 32768){
    int j = idx >> 6, b = idx & 63;
    ksT[j*64 + b] = keysum[b*512 + j] * C;
    vsT[j*64 + b] = valsum[b*512 + j];
  } else if (idx < 98304){
    hbuf[idx - 32768] = 0.f;                         // both h double-buffers = 0
  } else if (idx < 102400){
    int r = idx - 98304; int b = r >> 6, v = r & 63;
    out[b*12800 + v] = 0.f;                          // logits[:,0,:]
  } else if (idx < 102464){
    int b = idx - 102400;
    out[819200 + b*200] = 0.f;                       // symbols[:,0]
  } else if (idx < 102528){
    bar[idx - 102464] = 0u;
  }
}

// ---------------- main persistent loop kernel ----------------
// 256 blocks x 512 thr (1/CU). Block owns gate rows r=0..7 for cells {2blk, 2blk+1}.
// Per iteration s (s=0..199): one fused pass over j=0..511 computes
//   Gh = Wh@h(s), Gc = Wc@(valsum*e), S_b = sum_j e,  e = exp2(ksT*h)
//   gates = Gh + Gc/S_b + tok  -> h(s+1)  (s<199 meaningful; s=199 harmless)
//   logit rows (blocks 0..63): L = cdn_h@h + (cdn_c@(valsum*e))/S_b + cdn_b  (stored s>=1)
//   sampling of row s-1 (blocks 192..255) at iteration start, pipelined.
// ONE grid barrier per iteration.
__global__ __launch_bounds__(GTHR, 2) void k_loop(
    const float* __restrict__ w_ih, const float* __restrict__ w_hh,
    const int* __restrict__ batch_y, const float* __restrict__ tok,
    const float* __restrict__ ksT, const float* __restrict__ vsT,
    const float* __restrict__ cdn_w, const float* __restrict__ cdn_b,
    float* __restrict__ hbuf, float* __restrict__ logits_c,
    float* __restrict__ out, unsigned* __restrict__ bar){
  __shared__ float W_lds[512][16];     // [j][slot]: 0..7 Wc, 8..15 Wh
  __shared__ float cdn_lds[512][2];    // [j][{h,c}] (blocks<64)
  __shared__ float redH[8][8][64];     // [wave][r][b]
  __shared__ float redC[8][8][64];
  __shared__ float redS[8][64];        // [wave][b]
  __shared__ float redLh[8][64];
  __shared__ float redLc[8][64];
  __shared__ float gates_lds[8][64];
  __shared__ float cc_lds[2][64];

  unsigned* cnt = bar;
  unsigned* gen = bar + 16;

  const int tid = threadIdx.x;
  const int blk = blockIdx.x;
  const bool HASL = (blk < 64);

  // stage weights: W_lds[j][t]
  for (int idx = tid; idx < 8192; idx += GTHR){
    int t = idx >> 9, j = idx & 511;
    int r = t & 7;
    int row = ((r >> 1) << 9) + blk*2 + (r & 1);
    W_lds[j][t] = (t < 8) ? w_ih[row*1024 + 512 + j] : w_hh[row*512 + j];
  }
  if (HASL && tid < 512){
    cdn_lds[tid][0] = cdn_w[blk*1024 + tid];
    cdn_lds[tid][1] = cdn_w[blk*1024 + 512 + tid];
  }
  float cdnb = HASL ? cdn_b[blk] : 0.f;
  if (tid < 128) cc_lds[tid >> 6][tid & 63] = 0.0f;
  __syncthreads();

  const int w = tid >> 6, l = tid & 63, kg = l >> 4, bg = l & 15;
  const int rr = tid >> 6, rb = tid & 63;
  const unsigned volane = (unsigned)((((w*64 + kg) << 6) | (bg << 2)) << 2); // byte off in [j][64] f32

#define LOADC(R, PTR, VOFF) asm volatile("global_load_dwordx4 %0, %1, %2 sc0 sc1" : "=v"(R) : "v"(VOFF), "s"(PTR))
#define LOADN(R, PTR, VOFF) asm volatile("global_load_dwordx4 %0, %1, %2" : "=v"(R) : "v"(VOFF), "s"(PTR))
#define WAITV(N) do{ asm volatile("s_waitcnt vmcnt(" #N ")" ::: "memory"); \
  __builtin_amdgcn_sched_barrier(0); }while(0)

  for (int s = 0; s <= NSTEP; ++s){
    const float* hin  = hbuf + (s & 1)*32768;
    float*       hout = hbuf + ((s + 1) & 1)*32768;

    // ---- pipelined sampling of row s-1 (blocks 192..255) ----
    if (blk >= 192 && s >= 2){
      int b = blk - 192;
      if (tid < 64){
        const float* lc = logits_c + ((s - 1) & 1)*4096;
        unsigned vo = (unsigned)((tid*64 + b) << 2);
        float lg;
        asm volatile("global_load_dword %0, %1, %2 sc0 sc1" : "=v"(lg) : "v"(vo), "s"(lc));
        asm volatile("s_waitcnt vmcnt(0)" ::: "memory");
        float z = gumbel_tf((unsigned)((b*199 + s - 2)*64 + tid)) + lg;
        int idx = tid;
        #pragma unroll
        for (int mm = 1; mm < 64; mm <<= 1){
          float oz = __shfl_xor(z, mm, 64);
          int   oi = __shfl_xor(idx, mm, 64);
          if (oz > z || (oz == z && oi < idx)){ z = oz; idx = oi; }
        }
        if (tid == 0) out[819200 + b*200 + (s - 1)] = (float)idx;
      }
      WAITV(0);   // drain symbol store before entering counted pipeline
    }

    // ---- fused pass over j ----
    f4v Gh[8], Gc[8], Sv, Lh, Lc;
    #pragma unroll
    for (int r = 0; r < 8; ++r){ Gh[r] = 0.f; Gc[r] = 0.f; }
    Sv = 0.f; Lh = 0.f; Lc = 0.f;

    f4v xv[4], kv4[4], vv4[4];
    #pragma unroll
    for (int jj = 0; jj < 4; ++jj){
      unsigned vo = volane + (unsigned)jj*1024u;
      LOADC(xv[jj],  hin, vo);
      LOADN(kv4[jj], ksT, vo);
      LOADN(vv4[jj], vsT, vo);
    }

    #pragma unroll
    for (int jj = 0; jj < 16; ++jj){
      if (jj <= 12) WAITV(9); else if (jj == 13) WAITV(6); else if (jj == 14) WAITV(3); else WAITV(0);
      const int bank = jj & 3;
      const int j0 = w*64 + kg + jj*4;
      f4v x4 = xv[bank], k4 = kv4[bank], v4 = vv4[bank];
      // e = exp2(ksT*h);  t = valsum*e
      f4v e4;
      e4.x = exp2f(k4.x*x4.x); e4.y = exp2f(k4.y*x4.y);
      e4.z = exp2f(k4.z*x4.z); e4.w = exp2f(k4.w*x4.w);
      Sv += e4;
      f4v t4 = v4 * e4;
      f4v wcA = *(const f4v*)&W_lds[j0][0];
      f4v wcB = *(const f4v*)&W_lds[j0][4];
      f4v whA = *(const f4v*)&W_lds[j0][8];
      f4v whB = *(const f4v*)&W_lds[j0][12];
      float wc[8] = {wcA.x,wcA.y,wcA.z,wcA.w,wcB.x,wcB.y,wcB.z,wcB.w};
      float wh[8] = {whA.x,whA.y,whA.z,whA.w,whB.x,whB.y,whB.z,whB.w};
      #pragma unroll
      for (int r = 0; r < 8; ++r){
        Gc[r].x = fmaf(wc[r], t4.x, Gc[r].x); Gh[r].x = fmaf(wh[r], x4.x, Gh[r].x);
        Gc[r].y = fmaf(wc[r], t4.y, Gc[r].y); Gh[r].y = fmaf(wh[r], x4.y, Gh[r].y);
        Gc[r].z = fmaf(wc[r], t4.z, Gc[r].z); Gh[r].z = fmaf(wh[r], x4.z, Gh[r].z);
        Gc[r].w = fmaf(wc[r], t4.w, Gc[r].w); Gh[r].w = fmaf(wh[r], x4.w, Gh[r].w);
      }
      if (HASL){
        float ch = cdn_lds[j0][0], cc = cdn_lds[j0][1];
        Lh.x = fmaf(ch, x4.x, Lh.x); Lc.x = fmaf(cc, t4.x, Lc.x);
        Lh.y = fmaf(ch, x4.y, Lh.y); Lc.y = fmaf(cc, t4.y, Lc.y);
        Lh.z = fmaf(ch, x4.z, Lh.z); Lc.z = fmaf(cc, t4.z, Lc.z);
        Lh.w = fmaf(ch, x4.w, Lh.w); Lc.w = fmaf(cc, t4.w, Lc.w);
      }
      if (jj < 12){
        unsigned vo = volane + (unsigned)(jj + 4)*1024u;
        LOADC(xv[bank],  hin, vo);
        LOADN(kv4[bank], ksT, vo);
        LOADN(vv4[bank], vsT, vo);
      }
    }

    // token-gate prefetch (L2-hot), used at assembly
    int yprev = (s == 0) ? 0 : batch_y[rb*200 + s];
    float tokval = tok[yprev*2048 + (rr >> 1)*512 + blk*2 + (rr & 1)];

    // ---- reduce over kg lanes (^16, ^32) ----
    #pragma unroll
    for (int r = 0; r < 8; ++r)
      #pragma unroll
      for (int q = 0; q < 4; ++q){
        float a = Gh[r][q]; a += __shfl_xor(a, 16, 64); a += __shfl_xor(a, 32, 64); Gh[r][q] = a;
        float c = Gc[r][q]; c += __shfl_xor(c, 16, 64); c += __shfl_xor(c, 32, 64); Gc[r][q] = c;
      }
    #pragma unroll
    for (int q = 0; q < 4; ++q){
      float a = Sv[q]; a += __shfl_xor(a, 16, 64); a += __shfl_xor(a, 32, 64); Sv[q] = a;
      float lh = Lh[q]; lh += __shfl_xor(lh, 16, 64); lh += __shfl_xor(lh, 32, 64); Lh[q] = lh;
      float lcv = Lc[q]; lcv += __shfl_xor(lcv, 16, 64); lcv += __shfl_xor(lcv, 32, 64); Lc[q] = lcv;
    }
    if (l < 16){
      #pragma unroll
      for (int r = 0; r < 8; ++r){
        *(f4v*)&redH[w][r][bg*4] = Gh[r];
        *(f4v*)&redC[w][r][bg*4] = Gc[r];
      }
      *(f4v*)&redS[w][bg*4]  = Sv;
      *(f4v*)&redLh[w][bg*4] = Lh;
      *(f4v*)&redLc[w][bg*4] = Lc;
    }
    __syncthreads();

    // ---- assembly: gates, nonlinearity, h-store ----
    {
      float gh = 0.f, gc = 0.f, Sb = 0.f;
      #pragma unroll
      for (int ww = 0; ww < 8; ++ww){
        gh += redH[ww][rr][rb];
        gc += redC[ww][rr][rb];
        Sb += redS[ww][rb];
      }
      gates_lds[rr][rb] = gh + gc/Sb + tokval;
    }
    __syncthreads();
    if (tid < 128){
      int c = tid >> 6, b = tid & 63;
      float ig = gates_lds[0 + c][b];
      float fg = gates_lds[2 + c][b];
      float gg = gates_lds[4 + c][b];
      float og = gates_lds[6 + c][b];
      float cprev = cc_lds[c][b];
      float cnew = sigf(fg)*cprev + sigf(ig)*tanhf(gg);
      float hnew = sigf(og)*tanhf(cnew);
      cc_lds[c][b] = cnew;
      float oldh = __hip_atomic_exchange(&hout[(blk*2 + c)*64 + b], hnew, RLX, AGENT);
      asm volatile("" :: "v"(oldh));
    }

    // ---- logit row v=blk (blocks 0..63), stored for s>=1 ----
    if (HASL && s >= 1 && tid < 64){
      int b = tid;
      float lh = 0.f, lcv = 0.f, Sb = 0.f;
      #pragma unroll
      for (int ww = 0; ww < 8; ++ww){
        lh += redLh[ww][b]; lcv += redLc[ww][b]; Sb += redS[ww][b];
      }
      float logit = lh + lcv/Sb + cdnb;
      out[b*12800 + s*64 + blk] = logit;
      float* lc = logits_c + (s & 1)*4096;
      float oldl = __hip_atomic_exchange(&lc[blk*64 + b], logit, RLX, AGENT);
      asm volatile("" :: "v"(oldl));
    }

    gbar(cnt, gen, (unsigned)(s + 1));
  }

  // ---- epilogue: sample last row (199) ----
  if (blk >= 192){
    int b = blk - 192;
    if (tid < 64){
      const float* lc = logits_c + (NSTEP & 1)*4096;
      unsigned vo = (unsigned)((tid*64 + b) << 2);
      float lg;
      asm volatile("global_load_dword %0, %1, %2 sc0 sc1" : "=v"(lg) : "v"(vo), "s"(lc));
      asm volatile("s_waitcnt vmcnt(0)" ::: "memory");
      float z = gumbel_tf((unsigned)((b*199 + 198)*64 + tid)) + lg;
      int idx = tid;
      #pragma unroll
      for (int mm = 1; mm < 64; mm <<= 1){
        float oz = __shfl_xor(z, mm, 64);
        int   oi = __shfl_xor(idx, mm, 64);
        if (oz > z || (oz == z && oi < idx)){ z = oz; idx = oi; }
      }
      if (tid == 0) out[819200 + b*200 + 199] = (float)idx;
    }
  }
#undef LOADC
#undef LOADN
#undef WAITV
}

// ---------------- launcher ----------------
extern "C" void kernel_launch(void* const* d_in, const int* in_sizes, int n_in,
                              void* d_out, int out_size, void* d_ws, size_t ws_size,
                              hipStream_t stream){
  const float* seq     = (const float*)d_in[0];
  const float* key_w   = (const float*)d_in[1];
  const float* key_b   = (const float*)d_in[2];
  const float* value_w = (const float*)d_in[3];
  const float* value_b = (const float*)d_in[4];
  const float* char_e  = (const float*)d_in[5];
  const float* w_ih    = (const float*)d_in[6];
  const float* w_hh    = (const float*)d_in[7];
  const float* b_ih    = (const float*)d_in[8];
  const float* b_hh    = (const float*)d_in[9];
  const float* cdn_w   = (const float*)d_in[10];
  const float* cdn_b   = (const float*)d_in[11];
  const int*   lens    = (const int*)d_in[12];
  const int*   batch_y = (const int*)d_in[13];
  float* out = (float*)d_out;
  float* ws  = (float*)d_ws;

  float* msum_part = ws;              // 262144
  float* msumT     = ws + 262144;     // 32768   [h][b]
  float* keysum    = ws + 294912;     // 32768   [b][i]
  float* valsum    = ws + 327680;     // 32768   [b][i]
  float* tok       = ws + 360448;     // 131072  [v][row]
  float* ceT       = ws + 491520;     // 32768   [e][v]
  float* ksT       = ws + 524288;     // 32768   [j][b] scaled
  float* vsT       = ws + 557056;     // 32768   [j][b]
  float* hbuf      = ws + 589824;     // 65536   2 x [row][b]
  float* logits_c  = ws + 655360;     // 8192    2 x [v][b]
  unsigned* bar    = (unsigned*)(ws + 663552); // [0]=cnt, [16]=gen

  k_msum_part<<<512, 256, 0, stream>>>(seq, lens, msum_part);
  k_msum     <<<64,  256, 0, stream>>>(msum_part, msumT);
  k_kv       <<<256, 256, 0, stream>>>(msumT, key_w, key_b, value_w, value_b, keysum, valsum);
  k_ceT      <<<128, 256, 0, stream>>>(char_e, ceT);
  k_tok      <<<512, 256, 0, stream>>>(ceT, w_ih, b_ih, b_hh, tok);
  k_init     <<<401, 256, 0, stream>>>(keysum, valsum, ksT, vsT, hbuf, out, bar);

  k_loop<<<GBLK, GTHR, 0, stream>>>(w_ih, w_hh, batch_y, tok, ksT, vsT,
                                    cdn_w, cdn_b, hbuf, logits_c, out, bar);
  (void)in_sizes; (void)n_in; (void)out_size; (void)ws_size;
}

// Round 8
// 5926.909 us; speedup vs baseline: 1.8989x; 1.8989x over previous
//
#include <hip/hip_runtime.h>
#include <math.h>

#define NB 64      // batch
#define NH 512     // hidden
#define NV 64      // vocab
#define NT 200     // T
#define NSTEP 199
#define GBLK 256   // main-loop blocks
#define GTHR 512   // threads per block

#define RLX   __ATOMIC_RELAXED
#define AGENT __HIP_MEMORY_SCOPE_AGENT

typedef float f4v __attribute__((ext_vector_type(4)));

// ---------------- threefry / gumbel --------------------------------------
// jax.random.categorical(jax.random.key(1),...) with jax_threefry_partitionable=True:
// bits = x0^x1 of threefry2x32(key=(0,1), counter=(0, flat_index))
__device__ inline float gumbel_tf(unsigned f){
  const unsigned ksc[3] = {0u, 1u, 0x1BD11BDBu};
  unsigned x0 = 0u + ksc[0];
  unsigned x1 = f  + ksc[1];
  const int R0[4] = {13,15,26,6};
  const int R1[4] = {17,29,16,24};
  #pragma unroll
  for (int i = 0; i < 5; ++i){
    #pragma unroll
    for (int r = 0; r < 4; ++r){
      int rot = (i & 1) ? R1[r] : R0[r];
      x0 += x1;
      x1 = (x1 << rot) | (x1 >> (32 - rot));
      x1 ^= x0;
    }
    x0 += ksc[(i+1)%3];
    x1 += ksc[(i+2)%3] + (unsigned)(i+1);
  }
  unsigned bits = x0 ^ x1;
  float u = __uint_as_float((bits >> 9) | 0x3F800000u) - 1.0f;
  u = fmaxf(u, 1.17549435e-38f);
  return -logf(-logf(u));
}

__device__ inline float sigf(float x){ return 1.0f/(1.0f + expf(-x)); }

// ---------------- grid barrier v2: per-block flag array + collector block.
// Monotone targets (no resets). Arrival: returning agent-scope atomic exchange
// to the block's OWN 64B-strided flag (no shared RMW line). Collector (block
// 128) polls all 256 flags with 256 parallel threads, then sets gen; everyone
// polls gen. All data stores were drained (vmcnt(0)) before arrival, and all
// cross-block data uses the R3-proven sc0sc1/atomic-exchange discipline.
__device__ inline void gbar2(unsigned* flags, unsigned* gen, int blk, unsigned tgt){
  asm volatile("s_waitcnt vmcnt(0)" ::: "memory");
  __syncthreads();
  const int tid = threadIdx.x;
  if (tid == 0){
    unsigned o = __hip_atomic_exchange(&flags[blk*16], tgt, RLX, AGENT);
    asm volatile("" :: "v"(o));
  }
  if (blk == 128){
    if (tid < 256){
      while (__hip_atomic_load(&flags[tid*16], RLX, AGENT) < tgt){
        __builtin_amdgcn_s_sleep(1);
      }
    }
    __syncthreads();
    if (tid == 0){
      unsigned o = __hip_atomic_exchange(gen, tgt, RLX, AGENT);
      asm volatile("" :: "v"(o));
    }
  }
  if (tid == 0){
    while (__hip_atomic_load(gen, RLX, AGENT) < tgt){
      __builtin_amdgcn_s_sleep(1);
    }
  }
  __syncthreads();
}

// ---------------- block reductions (512 threads = 8 waves) ----------------
__device__ inline float blk_red_max(float v, float* scr){
  #pragma unroll
  for (int m = 1; m < 64; m <<= 1) v = fmaxf(v, __shfl_xor(v, m, 64));
  if ((threadIdx.x & 63) == 0) scr[threadIdx.x >> 6] = v;
  __syncthreads();
  float r = scr[0];
  #pragma unroll
  for (int i = 1; i < 8; ++i) r = fmaxf(r, scr[i]);
  __syncthreads();
  return r;
}
__device__ inline float blk_red_sum(float v, float* scr){
  #pragma unroll
  for (int m = 1; m < 64; m <<= 1) v += __shfl_xor(v, m, 64);
  if ((threadIdx.x & 63) == 0) scr[threadIdx.x >> 6] = v;
  __syncthreads();
  float r = 0.f;
  #pragma unroll
  for (int i = 0; i < 8; ++i) r += scr[i];
  __syncthreads();
  return r;
}

// ---------------- precompute kernels (verbatim from passing R3) -----------
__global__ void k_msum_part(const float* __restrict__ emb, const int* __restrict__ lens,
                            float* __restrict__ part){
  int blk = blockIdx.x, b = blk >> 3, lc = blk & 7;
  int len = lens[b];
  int l0 = lc*64, l1 = len < l0+64 ? len : l0+64;
  for (int h = threadIdx.x; h < 512; h += 256){
    float a = 0.f;
    for (int l = l0; l < l1; ++l) a += emb[(b*512 + l)*512 + h];
    part[blk*512 + h] = a;
  }
}
__global__ void k_msum(const float* __restrict__ part, float* __restrict__ msumT){
  int b = blockIdx.x;
  for (int h = threadIdx.x; h < 512; h += 256){
    float a = 0.f;
    #pragma unroll
    for (int lc = 0; lc < 8; ++lc) a += part[(b*8+lc)*512 + h];
    msumT[h*64 + b] = a;
  }
}
__global__ void k_kv(const float* __restrict__ msumT,
                     const float* __restrict__ kw, const float* __restrict__ kb,
                     const float* __restrict__ vw, const float* __restrict__ vb,
                     float* __restrict__ keysum, float* __restrict__ valsum){
  int which = blockIdx.x >> 7;
  int i = ((blockIdx.x & 127) << 2) + (threadIdx.x >> 6);
  int b = threadIdx.x & 63;
  const float* W = which ? vw : kw;
  float a = 0.f;
  for (int h = 0; h < 512; ++h) a = fmaf(msumT[h*64+b], W[i*512+h], a);
  float bias = which ? vb[i] : kb[i];
  float* out = which ? valsum : keysum;
  out[b*512 + i] = a + 512.0f*bias;
}
__global__ void k_ceT(const float* __restrict__ ce, float* __restrict__ ceT){
  int idx = blockIdx.x*256 + threadIdx.x;
  if (idx < 32768){ int v = idx >> 9, e = idx & 511; ceT[e*64 + v] = ce[v*512 + e]; }
}
__global__ void k_tok(const float* __restrict__ ceT, const float* __restrict__ w_ih,
                      const float* __restrict__ b_ih, const float* __restrict__ b_hh,
                      float* __restrict__ tok){
  int idx = blockIdx.x*256 + threadIdx.x;
  int v = idx & 63, row = idx >> 6;
  float a = 0.f;
  for (int e = 0; e < 512; ++e) a = fmaf(ceT[e*64+v], w_ih[row*1024 + e], a);
  tok[v*2048 + row] = a + b_ih[row] + b_hh[row];
}
// cdnT transpose, xT[0] init (ctx0 = valsum/512, hh0 = 0), t=0 outputs, barrier zeroing
__global__ void k_init(const float* __restrict__ valsum, const float* __restrict__ cdn_w,
                       float* __restrict__ cdnT, float* __restrict__ xT,
                       float* __restrict__ out, unsigned* __restrict__ bar){
  int idx = blockIdx.x*256 + threadIdx.x;
  if (idx < 65536){
    int v = idx >> 10, k = idx & 1023;
    cdnT[k*64 + v] = cdn_w[idx];
  } else if (idx < 98304){
    int r = idx - 65536; int j = r >> 6, b = r & 63;
    xT[j*64 + b] = valsum[b*512 + j] * (1.0f/512.0f);
  } else if (idx < 131072){
    xT[idx - 65536] = 0.f;
  } else if (idx < 135168){
    int r = idx - 131072; int b = r >> 6, v = r & 63;
    out[b*12800 + v] = 0.f;
  } else if (idx < 135232){
    int b = idx - 135168;
    out[819200 + b*200] = 0.f;
  } else if (idx < 139392){
    bar[idx - 135232] = 0u;   // flags[256*16] + gen
  }
}

// ---------------- main persistent loop kernel ----------------
// ARITHMETIC VERBATIM from the PASSING 6.83ms R3 kernel (two-phase, explicit
// softmax Phase B). Only the barrier implementation changed (gbar -> gbar2).
__global__ __launch_bounds__(GTHR, 2) void k_loop(
    const float* __restrict__ w_ih, const float* __restrict__ w_hh,
    const int* __restrict__ batch_y, const float* __restrict__ tok,
    const float* __restrict__ keysum, const float* __restrict__ valsum,
    const float* __restrict__ cdnT, const float* __restrict__ cdn_b,
    float* __restrict__ xT, float* __restrict__ out,
    unsigned* __restrict__ bar){
  __shared__ float W_lds[1024][8];     // [k][r], r = gate*2 + cell
  __shared__ float red[8][8][64];      // [wave][r][b]
  __shared__ float gates_lds[8][64];
  __shared__ float cc_lds[2][64];
  __shared__ float pb_h[512], pb_c[512];
  __shared__ float pb_lp[8][64];
  __shared__ float scr[8];

  unsigned* flags = bar;
  unsigned* gen   = bar + 4096;

  const int tid = threadIdx.x;
  const int blk = blockIdx.x;

  for (int idx = tid; idx < 8192; idx += GTHR){
    int k = idx >> 3, r = idx & 7;
    int g = r >> 1, c = r & 1;
    int row = g*512 + blk*2 + c;
    W_lds[k][r] = (k < 512) ? w_ih[row*1024 + 512 + k] : w_hh[row*512 + (k - 512)];
  }
  if (tid < 128) cc_lds[tid >> 6][tid & 63] = 0.0f;
  __syncthreads();

  const int w = tid >> 6, l = tid & 63, kg = l >> 4, bg = l & 15;
  const float SCALE = 22.627416997969522f;   // sqrt(512)
  int p = 0;

#define ISS1(R, JJ) do{ const float* _p = xin + (((kbase + (JJ)*4) << 6) | (bg << 2)); \
  asm volatile("global_load_dwordx4 %0, %1, off sc0 sc1" : "=v"(R) : "v"(_p)); }while(0)
#define ISS8(P, J0) do{ ISS1(P##0,(J0)+0);ISS1(P##1,(J0)+1);ISS1(P##2,(J0)+2);ISS1(P##3,(J0)+3); \
  ISS1(P##4,(J0)+4);ISS1(P##5,(J0)+5);ISS1(P##6,(J0)+6);ISS1(P##7,(J0)+7); }while(0)
#define CMP1(R, JJ) do{ int _k = kbase + (JJ)*4; \
  f4v _wA = *(const f4v*)&W_lds[_k][0]; f4v _wB = *(const f4v*)&W_lds[_k][4]; \
  float _wv[8] = {_wA.x,_wA.y,_wA.z,_wA.w,_wB.x,_wB.y,_wB.z,_wB.w}; \
  float _xv[4] = {R.x,R.y,R.z,R.w}; \
  _Pragma("unroll") for (int _r = 0; _r < 8; ++_r){ \
    _Pragma("unroll") for (int _q = 0; _q < 4; ++_q) \
      acc[_r][_q] = fmaf(_wv[_r], _xv[_q], acc[_r][_q]); } }while(0)
#define CMP8(P, J0) do{ CMP1(P##0,(J0)+0);CMP1(P##1,(J0)+1);CMP1(P##2,(J0)+2);CMP1(P##3,(J0)+3); \
  CMP1(P##4,(J0)+4);CMP1(P##5,(J0)+5);CMP1(P##6,(J0)+6);CMP1(P##7,(J0)+7); }while(0)
#define WAITV(N) do{ asm volatile("s_waitcnt vmcnt(" #N ")" ::: "memory"); \
  __builtin_amdgcn_sched_barrier(0); }while(0)

  for (int s = 0; s < NSTEP; ++s){
    const float* xin  = xT + p*65536;
    float*       xout = xT + (p^1)*65536;

    // prefetch token-gate value for the reduce phase (L2-hot normal loads)
    const int rr = tid >> 6, rb = tid & 63;
    int yprev = (s == 0) ? 0 : batch_y[rb*200 + s];
    float tokval = tok[yprev*2048 + (rr >> 1)*512 + blk*2 + (rr & 1)];

    // ---- Phase A: gates via counted-vmcnt pipelined sc1 loads ----
    float acc[8][4];
    #pragma unroll
    for (int r = 0; r < 8; ++r)
      #pragma unroll
      for (int q = 0; q < 4; ++q) acc[r][q] = 0.f;

    const int kbase = w*128 + kg;
    {
      f4v A0,A1,A2,A3,A4,A5,A6,A7,B0,B1,B2,B3,B4,B5,B6,B7;
      ISS8(A, 0);
      ISS8(B, 8);
      WAITV(8); CMP8(A, 0);
      ISS8(A, 16);
      WAITV(8); CMP8(B, 8);
      ISS8(B, 24);
      WAITV(8); CMP8(A, 16);
      WAITV(0); CMP8(B, 24);
    }

    // reduce across kg (lanes ^16, ^32)
    #pragma unroll
    for (int r = 0; r < 8; ++r)
      #pragma unroll
      for (int q = 0; q < 4; ++q){
        float v = acc[r][q];
        v += __shfl_xor(v, 16, 64);
        v += __shfl_xor(v, 32, 64);
        acc[r][q] = v;
      }
    if (l < 16){
      #pragma unroll
      for (int r = 0; r < 8; ++r)
        *(float4*)&red[w][r][bg*4] = make_float4(acc[r][0], acc[r][1], acc[r][2], acc[r][3]);
    }
    __syncthreads();
    {
      float g = 0.f;
      #pragma unroll
      for (int ww = 0; ww < 8; ++ww) g += red[ww][rr][rb];
      gates_lds[rr][rb] = g + tokval;
    }
    __syncthreads();
    if (tid < 128){
      int c = tid >> 6, b = tid & 63;
      float ig = gates_lds[0 + c][b];
      float fg = gates_lds[2 + c][b];
      float gg = gates_lds[4 + c][b];
      float og = gates_lds[6 + c][b];
      float cprev = cc_lds[c][b];
      float cnew = sigf(fg)*cprev + sigf(ig)*tanhf(gg);
      float hnew = sigf(og)*tanhf(cnew);
      cc_lds[c][b] = cnew;
      float oldh = __hip_atomic_exchange(&xout[(512 + blk*2 + c)*64 + b], hnew, RLX, AGENT);
      asm volatile("" :: "v"(oldh));
    }
    gbar2(flags, gen, blk, (unsigned)(2*s + 1));

    // ---- Phase B: attend + logits + sampling (blocks 0..63, one per batch) ----
    if (blk < 64){
      int b = blk;
      int jj = tid;
      float h = __hip_atomic_load(&xout[(512 + jj)*64 + b], RLX, AGENT);
      pb_h[jj] = h;
      float sc = (keysum[b*512 + jj] * h) / SCALE;
      float m = blk_red_max(sc, scr);
      float e = expf(sc - m);
      float S = blk_red_sum(e, scr);
      float cx = valsum[b*512 + jj] * (e / S);
      pb_c[jj] = cx;
      float oldc = __hip_atomic_exchange(&xout[jj*64 + b], cx, RLX, AGENT);
      asm volatile("" :: "v"(oldc));
      __syncthreads();
      int kq = tid >> 6, v = tid & 63;
      float part = 0.f;
      for (int k = kq*128; k < kq*128 + 128; ++k){
        float xh = (k < 512) ? pb_h[k] : pb_c[k - 512];
        part = fmaf(cdnT[k*64 + v], xh, part);
      }
      pb_lp[kq][v] = part;
      __syncthreads();
      if (tid < 64){
        int v2 = tid;
        float logit = cdn_b[v2];
        #pragma unroll
        for (int q = 0; q < 8; ++q) logit += pb_lp[q][v2];
        out[b*12800 + (s+1)*64 + v2] = logit;
        float z = gumbel_tf((unsigned)((b*199 + s)*64 + v2)) + logit;
        int idx = v2;
        #pragma unroll
        for (int mm = 1; mm < 64; mm <<= 1){
          float oz = __shfl_xor(z, mm, 64);
          int   oi = __shfl_xor(idx, mm, 64);
          if (oz > z || (oz == z && oi < idx)){ z = oz; idx = oi; }
        }
        if (v2 == 0) out[819200 + b*200 + (s+1)] = (float)idx;
      }
    }
    gbar2(flags, gen, blk, (unsigned)(2*s + 2));
    p ^= 1;
  }
#undef ISS1
#undef ISS8
#undef CMP1
#undef CMP8
#undef WAITV
}

// ---------------- launcher ----------------
extern "C" void kernel_launch(void* const* d_in, const int* in_sizes, int n_in,
                              void* d_out, int out_size, void* d_ws, size_t ws_size,
                              hipStream_t stream){
  const float* seq     = (const float*)d_in[0];
  const float* key_w   = (const float*)d_in[1];
  const float* key_b   = (const float*)d_in[2];
  const float* value_w = (const float*)d_in[3];
  const float* value_b = (const float*)d_in[4];
  const float* char_e  = (const float*)d_in[5];
  const float* w_ih    = (const float*)d_in[6];
  const float* w_hh    = (const float*)d_in[7];
  const float* b_ih    = (const float*)d_in[8];
  const float* b_hh    = (const float*)d_in[9];
  const float* cdn_w   = (const float*)d_in[10];
  const float* cdn_b   = (const float*)d_in[11];
  const int*   lens    = (const int*)d_in[12];
  const int*   batch_y = (const int*)d_in[13];
  float* out = (float*)d_out;
  float* ws  = (float*)d_ws;

  float* msum_part = ws;              // 262144
  float* msumT     = ws + 262144;     // 32768   [h][b]
  float* keysum    = ws + 294912;     // 32768   [b][i]
  float* valsum    = ws + 327680;     // 32768   [b][i]
  float* tok       = ws + 360448;     // 131072  [v][row]
  float* cdnT      = ws + 491520;     // 65536   [k][v]
  float* ceT       = ws + 557056;     // 32768   [e][v]
  float* xT        = ws + 589824;     // 131072  2 x [k][b]
  unsigned* bar    = (unsigned*)(ws + 720896); // flags[4096] + gen

  k_msum_part<<<512, 256, 0, stream>>>(seq, lens, msum_part);
  k_msum     <<<64,  256, 0, stream>>>(msum_part, msumT);
  k_kv       <<<256, 256, 0, stream>>>(msumT, key_w, key_b, value_w, value_b, keysum, valsum);
  k_ceT      <<<128, 256, 0, stream>>>(char_e, ceT);
  k_tok      <<<512, 256, 0, stream>>>(ceT, w_ih, b_ih, b_hh, tok);
  k_init     <<<545, 256, 0, stream>>>(valsum, cdn_w, cdnT, xT, out, bar);

  k_loop<<<GBLK, GTHR, 0, stream>>>(w_ih, w_hh, batch_y, tok, keysum, valsum,
                                    cdnT, cdn_b, xT, out, bar);
  (void)in_sizes; (void)n_in; (void)out_size; (void)ws_size;
}